// Round 1
// baseline (1004.930 us; speedup 1.0000x reference)
//
#include <hip/hip_runtime.h>
#include <hip/hip_bf16.h>

#define N_NODES 100000
#define N_EDGES 1600000

// ---------------- scatter: one wave (64 lanes) per edge ----------------
// lane f handles feature f. Gather x[src] row (coalesced 256B), atomicAdd into
// agg[dst] row. Lane 0 optionally bumps degree.
__global__ void scatter_add_kernel(const float* __restrict__ x,
                                   const int* __restrict__ src,
                                   const int* __restrict__ dst,
                                   float* __restrict__ agg,
                                   float* __restrict__ deg,
                                   int n_edges, int do_deg) {
    int e = blockIdx.x * (blockDim.x >> 6) + (threadIdx.x >> 6);
    int f = threadIdx.x & 63;
    if (e >= n_edges) return;
    int s = src[e];
    int d = dst[e];
    float v = x[(size_t)s * 64 + f];
    atomicAdd(&agg[(size_t)d * 64 + f], v);
    if (do_deg && f == 0) atomicAdd(&deg[d], 1.0f);
}

// ---------------- transform1: x1 = relu((agg/deg) @ W1 + b1), [N,64] -------
// 64 threads per node; thread j computes output feature j. W1 staged in LDS.
__global__ void transform64_kernel(const float* __restrict__ agg,
                                   const float* __restrict__ deg,
                                   const float* __restrict__ W,
                                   const float* __restrict__ b,
                                   float* __restrict__ out, int n_nodes) {
    __shared__ float sW[64 * 64];
    __shared__ float sb[64];
    for (int i = threadIdx.x; i < 64 * 64; i += blockDim.x) sW[i] = W[i];
    if (threadIdx.x < 64) sb[threadIdx.x] = b[threadIdx.x];
    __syncthreads();

    int n = blockIdx.x * (blockDim.x >> 6) + (threadIdx.x >> 6);
    int j = threadIdx.x & 63;
    if (n >= n_nodes) return;

    float inv = 1.0f / fmaxf(deg[n], 1.0f);
    const float* arow = agg + (size_t)n * 64;
    float acc = sb[j];
    #pragma unroll
    for (int k = 0; k < 64; k++) {
        acc = fmaf(arow[k] * inv, sW[k * 64 + j], acc);
    }
    out[(size_t)n * 64 + j] = fmaxf(acc, 0.0f);
}

// ---------------- final: h = relu((agg/deg)@W2+b2) [N,32]; mean; sigmoid ---
// 64 threads per node (4 nodes / 256-thread block). Stage agg row in LDS,
// threads t<32 compute h[t], then lane 0 of the group reduces.
__global__ void final_kernel(const float* __restrict__ agg,
                             const float* __restrict__ deg,
                             const float* __restrict__ W2,
                             const float* __restrict__ b2,
                             const float* __restrict__ Wd,
                             const float* __restrict__ bd,
                             float* __restrict__ out, int n_nodes) {
    __shared__ float sW[64 * 32];
    __shared__ float sb[32];
    __shared__ float sa[4][64];
    __shared__ float sh[4][32];
    for (int i = threadIdx.x; i < 64 * 32; i += blockDim.x) sW[i] = W2[i];
    if (threadIdx.x < 32) sb[threadIdx.x] = b2[threadIdx.x];
    __syncthreads();

    int g = threadIdx.x >> 6;   // node group within block (0..3)
    int t = threadIdx.x & 63;
    int n = blockIdx.x * 4 + g;

    if (n < n_nodes) {
        float inv = 1.0f / fmaxf(deg[n], 1.0f);
        sa[g][t] = agg[(size_t)n * 64 + t] * inv;
    }
    __syncthreads();

    if (n < n_nodes && t < 32) {
        float acc = sb[t];
        #pragma unroll
        for (int k = 0; k < 64; k++) {
            acc = fmaf(sa[g][k], sW[k * 32 + t], acc);
        }
        sh[g][t] = fmaxf(acc, 0.0f);
    }
    __syncthreads();

    if (n < n_nodes && t == 0) {
        float m = 0.0f;
        #pragma unroll
        for (int j = 0; j < 32; j++) m += sh[g][j];
        m *= (1.0f / 32.0f);
        float z = fmaf(m, Wd[0], bd[0]);
        out[n] = 1.0f / (1.0f + __expf(-z));
    }
}

extern "C" void kernel_launch(void* const* d_in, const int* in_sizes, int n_in,
                              void* d_out, int out_size, void* d_ws, size_t ws_size,
                              hipStream_t stream) {
    const float* x    = (const float*)d_in[0];   // [N,64]
    const int*   esrc = (const int*)d_in[1];     // [E]
    const int*   edst = (const int*)d_in[2];     // [E]
    const float* W1   = (const float*)d_in[3];   // [64,64]
    const float* b1   = (const float*)d_in[4];   // [64]
    const float* W2   = (const float*)d_in[5];   // [64,32]
    const float* b2   = (const float*)d_in[6];   // [32]
    const float* Wd   = (const float*)d_in[7];   // [1,1]
    const float* bd   = (const float*)d_in[8];   // [1]
    float* out = (float*)d_out;                  // [N,1]

    // workspace layout (floats):
    //   deg  @ 0            (N, padded to 100096)
    //   agg  @ DEG_PAD      (N*64)  -- reused for layer1 and layer2 aggregation
    //   x1   @ DEG_PAD+N*64 (N*64)
    const size_t DEG_PAD = 100096;           // N rounded up to 128
    float* ws  = (float*)d_ws;
    float* deg = ws;
    float* agg = ws + DEG_PAD;
    float* x1  = ws + DEG_PAD + (size_t)N_NODES * 64;

    // zero deg + agg
    hipMemsetAsync(d_ws, 0, (DEG_PAD + (size_t)N_NODES * 64) * sizeof(float), stream);

    // layer 1 scatter (also computes degree)
    {
        int epb = 4; // 256 threads = 4 waves = 4 edges per block
        int blocks = (N_EDGES + epb - 1) / epb;
        scatter_add_kernel<<<blocks, 256, 0, stream>>>(x, esrc, edst, agg, deg, N_EDGES, 1);
    }
    // layer 1 transform -> x1
    {
        int npb = 4;
        int blocks = (N_NODES + npb - 1) / npb;
        transform64_kernel<<<blocks, 256, 0, stream>>>(agg, deg, W1, b1, x1, N_NODES);
    }
    // zero agg for layer 2
    hipMemsetAsync((void*)agg, 0, (size_t)N_NODES * 64 * sizeof(float), stream);
    // layer 2 scatter
    {
        int epb = 4;
        int blocks = (N_EDGES + epb - 1) / epb;
        scatter_add_kernel<<<blocks, 256, 0, stream>>>(x1, esrc, edst, agg, deg, N_EDGES, 0);
    }
    // layer 2 transform + mean + sigmoid -> out
    {
        int blocks = (N_NODES + 3) / 4;
        final_kernel<<<blocks, 256, 0, stream>>>(agg, deg, W2, b2, Wd, bd, out, N_NODES);
    }
}

// Round 2
// 668.059 us; speedup vs baseline: 1.5043x; 1.5043x over previous
//
#include <hip/hip_runtime.h>
#include <hip/hip_bf16.h>

#define N_NODES 100000
#define N_EDGES 1600000
#define N_PAD   100096          // N rounded up to 128
#define SCAN_TILE 1024
#define SCAN_NB   98            // ceil(N_NODES / SCAN_TILE)

// ---------- CSR build step 1: histogram of dst ----------
__global__ void hist_kernel(const int* __restrict__ dst, int* __restrict__ cnt, int n_edges) {
    int e = blockIdx.x * blockDim.x + threadIdx.x;
    if (e < n_edges) atomicAdd(&cnt[dst[e]], 1);
}

// ---------- CSR build step 2a: per-block reduce (1024 elems/block) ----------
__global__ void scan_reduce(const int* __restrict__ cnt, int* __restrict__ bsum, int n) {
    __shared__ int sred[256];
    int base = blockIdx.x * SCAN_TILE;
    int t = threadIdx.x;
    int sum = 0;
    #pragma unroll
    for (int i = 0; i < 4; i++) {
        int idx = base + t * 4 + i;
        sum += (idx < n) ? cnt[idx] : 0;
    }
    sred[t] = sum;
    __syncthreads();
    for (int off = 128; off >= 1; off >>= 1) {
        if (t < off) sred[t] += sred[t + off];
        __syncthreads();
    }
    if (t == 0) bsum[blockIdx.x] = sred[0];
}

// ---------- CSR build step 2b: scan the spine (<=128 block sums) ----------
__global__ void scan_spine(int* __restrict__ bsum, int nb) {
    __shared__ int s[128];
    int t = threadIdx.x;
    int v = (t < nb) ? bsum[t] : 0;
    s[t] = v;
    __syncthreads();
    for (int off = 1; off < 128; off <<= 1) {
        int u = (t >= off) ? s[t - off] : 0;
        __syncthreads();
        s[t] += u;
        __syncthreads();
    }
    if (t < nb) bsum[t] = s[t] - v;   // exclusive
}

// ---------- CSR build step 2c: per-block exclusive scan + offsets ----------
__global__ void scan_final(const int* __restrict__ cnt, const int* __restrict__ bsum,
                           int* __restrict__ row_ptr, int* __restrict__ cursor, int n) {
    __shared__ int ssum[256];
    int base = blockIdx.x * SCAN_TILE;
    int t = threadIdx.x;
    int v[4];
    int sum = 0;
    #pragma unroll
    for (int i = 0; i < 4; i++) {
        int idx = base + t * 4 + i;
        v[i] = (idx < n) ? cnt[idx] : 0;
        sum += v[i];
    }
    ssum[t] = sum;
    __syncthreads();
    for (int off = 1; off < 256; off <<= 1) {
        int u = (t >= off) ? ssum[t - off] : 0;
        __syncthreads();
        ssum[t] += u;
        __syncthreads();
    }
    int run = bsum[blockIdx.x] + ssum[t] - sum;  // exclusive prefix for this thread
    #pragma unroll
    for (int i = 0; i < 4; i++) {
        int idx = base + t * 4 + i;
        if (idx < n) { row_ptr[idx] = run; cursor[idx] = run; }
        run += v[i];
    }
}

// ---------- CSR build step 3: scatter edge sources into slots ----------
__global__ void csr_fill(const int* __restrict__ src, const int* __restrict__ dst,
                         int* __restrict__ cursor, int* __restrict__ col, int n_edges) {
    int e = blockIdx.x * blockDim.x + threadIdx.x;
    if (e < n_edges) {
        int pos = atomicAdd(&cursor[dst[e]], 1);
        col[pos] = src[e];
    }
}

// ---------- layer 1 fused: gather-mean(d=64) -> @W1+b1 -> relu -> @W2 ----------
// One wave per node; lane f = feature f. Never materializes agg or x1.
// z2[n,32] = relu(mean_agg(x)[n] @ W1 + b1) @ W2
__global__ void __launch_bounds__(256) layer1_fused(
    const float* __restrict__ x, const int* __restrict__ row_ptr,
    const int* __restrict__ col, const int* __restrict__ cnt,
    const float* __restrict__ W1, const float* __restrict__ b1,
    const float* __restrict__ W2, float* __restrict__ z2, int n_nodes)
{
    __shared__ float sW1[64 * 64];   // 16 KB
    __shared__ float sW2[64 * 32];   // 8 KB
    __shared__ float sa[4][64];      // mean-agg row per wave
    __shared__ float sh[4][64];      // hidden row per wave
    for (int i = threadIdx.x; i < 64 * 64; i += 256) sW1[i] = W1[i];
    for (int i = threadIdx.x; i < 64 * 32; i += 256) sW2[i] = W2[i];
    __syncthreads();

    int w = threadIdx.x >> 6;
    int f = threadIdx.x & 63;
    int n = blockIdx.x * 4 + w;
    bool valid = (n < n_nodes);
    int beg = valid ? row_ptr[n] : 0;
    int d   = valid ? cnt[n] : 0;

    float acc = 0.0f;
    for (int i = 0; i < d; i++) {
        int s = col[beg + i];                       // wave-uniform -> broadcast
        acc += x[(size_t)s * 64 + f];               // 256B coalesced row
    }
    sa[w][f] = acc / fmaxf((float)d, 1.0f);
    __syncthreads();

    // hidden = relu(sa @ W1 + b1)  — lane f computes output feature f
    float o = b1[f];
    #pragma unroll
    for (int k = 0; k < 64; k++) o = fmaf(sa[w][k], sW1[k * 64 + f], o);
    sh[w][f] = fmaxf(o, 0.0f);
    __syncthreads();

    // z2 = hidden @ W2 (no bias; bias folds in after aggregation)
    // lanes 0-31 cover k=0..31, lanes 32-63 cover k=32..63, combine via shfl
    int j  = f & 31;
    int hf = f >> 5;
    float z = 0.0f;
    #pragma unroll
    for (int kk = 0; kk < 32; kk++) {
        int k = hf * 32 + kk;
        z = fmaf(sh[w][k], sW2[k * 32 + j], z);
    }
    z += __shfl_down(z, 32);
    if (valid && hf == 0) z2[(size_t)n * 32 + j] = z;
}

// ---------- layer 2 fused: gather-mean(d=32) -> +b2 -> relu -> mean -> sigmoid ----------
// One wave per node. Lanes split edges 2-way: lane = j + 32*h handles feature j
// of edges i = h, h+2, h+4, ...
__global__ void __launch_bounds__(256) layer2_fused(
    const float* __restrict__ z2, const int* __restrict__ row_ptr,
    const int* __restrict__ col, const int* __restrict__ cnt,
    const float* __restrict__ b2, const float* __restrict__ Wd,
    const float* __restrict__ bd, float* __restrict__ out, int n_nodes)
{
    int n = blockIdx.x * 4 + (threadIdx.x >> 6);
    if (n >= n_nodes) return;
    int lane = threadIdx.x & 63;
    int j = lane & 31;
    int h = lane >> 5;
    int beg = row_ptr[n];
    int d   = cnt[n];

    float acc = 0.0f;
    for (int i = h; i < d; i += 2) {
        int s = col[beg + i];
        acc += z2[(size_t)s * 32 + j];
    }
    acc += __shfl_down(acc, 32);               // fold upper half into lanes 0-31
    float inv = 1.0f / fmaxf((float)d, 1.0f);
    float hj = fmaxf(fmaf(acc, inv, b2[j]), 0.0f);
    // mean over 32 features (lanes 0-31 hold valid hj; xor stays in-half)
    #pragma unroll
    for (int off = 16; off >= 1; off >>= 1) hj += __shfl_xor(hj, off);
    if (lane == 0) {
        float zv = fmaf(hj * (1.0f / 32.0f), Wd[0], bd[0]);
        out[n] = 1.0f / (1.0f + __expf(-zv));
    }
}

extern "C" void kernel_launch(void* const* d_in, const int* in_sizes, int n_in,
                              void* d_out, int out_size, void* d_ws, size_t ws_size,
                              hipStream_t stream) {
    const float* x    = (const float*)d_in[0];   // [N,64]
    const int*   esrc = (const int*)d_in[1];     // [E]
    const int*   edst = (const int*)d_in[2];     // [E]
    const float* W1   = (const float*)d_in[3];   // [64,64]
    const float* b1   = (const float*)d_in[4];   // [64]
    const float* W2   = (const float*)d_in[5];   // [64,32]
    const float* b2   = (const float*)d_in[6];   // [32]
    const float* Wd   = (const float*)d_in[7];   // [1,1]
    const float* bd   = (const float*)d_in[8];   // [1]
    float* out = (float*)d_out;                  // [N,1]

    // workspace layout:
    //   ints:  cnt[N_PAD] | row_ptr[N_PAD] | cursor[N_PAD] | bsum[128] | col[E]
    //   float: z2[N*32]
    int* wi      = (int*)d_ws;
    int* cnt     = wi;
    int* row_ptr = wi + N_PAD;
    int* cursor  = wi + 2 * N_PAD;
    int* bsum    = wi + 3 * N_PAD;
    int* col     = wi + 3 * N_PAD + 128;
    float* z2    = (float*)(col + N_EDGES);

    // zero the histogram
    hipMemsetAsync((void*)cnt, 0, N_PAD * sizeof(int), stream);

    // CSR build
    hist_kernel<<<(N_EDGES + 255) / 256, 256, 0, stream>>>(edst, cnt, N_EDGES);
    scan_reduce<<<SCAN_NB, 256, 0, stream>>>(cnt, bsum, N_NODES);
    scan_spine<<<1, 128, 0, stream>>>(bsum, SCAN_NB);
    scan_final<<<SCAN_NB, 256, 0, stream>>>(cnt, bsum, row_ptr, cursor, N_NODES);
    csr_fill<<<(N_EDGES + 255) / 256, 256, 0, stream>>>(esrc, edst, cursor, col, N_EDGES);

    // fused layers
    layer1_fused<<<(N_NODES + 3) / 4, 256, 0, stream>>>(
        x, row_ptr, col, cnt, W1, b1, W2, z2, N_NODES);
    layer2_fused<<<(N_NODES + 3) / 4, 256, 0, stream>>>(
        z2, row_ptr, col, cnt, b2, Wd, bd, out, N_NODES);
}

// Round 3
// 411.528 us; speedup vs baseline: 2.4419x; 1.6234x over previous
//
#include <hip/hip_runtime.h>
#include <hip/hip_bf16.h>

#define N_NODES 100000
#define N_EDGES 1600000
#define N_PAD   100096          // N rounded up to 128
#define SCAN_TILE 1024
#define SCAN_NB   98            // ceil(N_NODES / SCAN_TILE)

__device__ __forceinline__ unsigned short f32_to_bf16(float f) {
    unsigned int u = __float_as_uint(f);
    unsigned int r = (u + 0x7fffu + ((u >> 16) & 1u)) >> 16;
    return (unsigned short)r;
}
__device__ __forceinline__ float bf16_lo(unsigned int p) {   // low 16 bits
    return __uint_as_float(p << 16);
}
__device__ __forceinline__ float bf16_hi(unsigned int p) {   // high 16 bits
    return __uint_as_float(p & 0xffff0000u);
}

// ---------- CSR build step 1: histogram of dst ----------
__global__ void hist_kernel(const int* __restrict__ dst, int* __restrict__ cnt, int n_edges) {
    int e = blockIdx.x * blockDim.x + threadIdx.x;
    if (e < n_edges) atomicAdd(&cnt[dst[e]], 1);
}

// ---------- CSR build step 2a: per-block reduce (1024 elems/block) ----------
__global__ void scan_reduce(const int* __restrict__ cnt, int* __restrict__ bsum, int n) {
    __shared__ int sred[256];
    int base = blockIdx.x * SCAN_TILE;
    int t = threadIdx.x;
    int sum = 0;
    #pragma unroll
    for (int i = 0; i < 4; i++) {
        int idx = base + t * 4 + i;
        sum += (idx < n) ? cnt[idx] : 0;
    }
    sred[t] = sum;
    __syncthreads();
    for (int off = 128; off >= 1; off >>= 1) {
        if (t < off) sred[t] += sred[t + off];
        __syncthreads();
    }
    if (t == 0) bsum[blockIdx.x] = sred[0];
}

// ---------- CSR build step 2b: scan the spine (<=128 block sums) ----------
__global__ void scan_spine(int* __restrict__ bsum, int nb) {
    __shared__ int s[128];
    int t = threadIdx.x;
    int v = (t < nb) ? bsum[t] : 0;
    s[t] = v;
    __syncthreads();
    for (int off = 1; off < 128; off <<= 1) {
        int u = (t >= off) ? s[t - off] : 0;
        __syncthreads();
        s[t] += u;
        __syncthreads();
    }
    if (t < nb) bsum[t] = s[t] - v;   // exclusive
}

// ---------- CSR build step 2c: per-block exclusive scan + offsets ----------
__global__ void scan_final(const int* __restrict__ cnt, const int* __restrict__ bsum,
                           int* __restrict__ row_ptr, int* __restrict__ cursor, int n) {
    __shared__ int ssum[256];
    int base = blockIdx.x * SCAN_TILE;
    int t = threadIdx.x;
    int v[4];
    int sum = 0;
    #pragma unroll
    for (int i = 0; i < 4; i++) {
        int idx = base + t * 4 + i;
        v[i] = (idx < n) ? cnt[idx] : 0;
        sum += v[i];
    }
    ssum[t] = sum;
    __syncthreads();
    for (int off = 1; off < 256; off <<= 1) {
        int u = (t >= off) ? ssum[t - off] : 0;
        __syncthreads();
        ssum[t] += u;
        __syncthreads();
    }
    int run = bsum[blockIdx.x] + ssum[t] - sum;  // exclusive prefix for this thread
    #pragma unroll
    for (int i = 0; i < 4; i++) {
        int idx = base + t * 4 + i;
        if (idx < n) { row_ptr[idx] = run; cursor[idx] = run; }
        run += v[i];
    }
}

// ---------- CSR build step 3: scatter edge sources into slots ----------
__global__ void csr_fill(const int* __restrict__ src, const int* __restrict__ dst,
                         int* __restrict__ cursor, int* __restrict__ col, int n_edges) {
    int e = blockIdx.x * blockDim.x + threadIdx.x;
    if (e < n_edges) {
        int pos = atomicAdd(&cursor[dst[e]], 1);
        col[pos] = src[e];
    }
}

// ---------- dense GEMM: Y[M,64] = X[M,64] @ W[64,64], Y stored bf16 ----------
// 256 threads; 64 nodes/block; thread = (tm: node grp 0..15, tn: feat grp 0..15),
// 4x4 register blocking. sx padded to 65 (bank-conflict-free: 65 % 32 == 1).
__global__ void __launch_bounds__(256) gemm_n64(const float4* __restrict__ X4,
                                                const float* __restrict__ W,
                                                unsigned short* __restrict__ Y, int M) {
    __shared__ float sx[64][65];
    __shared__ float sw[64 * 64];
    int t = threadIdx.x;
    int base = blockIdx.x * 64;
    for (int i = t; i < 64 * 16; i += 256) {
        int r = i >> 4, c4 = i & 15;
        int row = base + r;
        float4 v = make_float4(0.f, 0.f, 0.f, 0.f);
        if (row < M) v = X4[(size_t)row * 16 + c4];
        sx[r][c4 * 4 + 0] = v.x; sx[r][c4 * 4 + 1] = v.y;
        sx[r][c4 * 4 + 2] = v.z; sx[r][c4 * 4 + 3] = v.w;
    }
    float4* sw4 = (float4*)sw;
    const float4* W4 = (const float4*)W;
    for (int i = t; i < 64 * 16; i += 256) sw4[i] = W4[i];
    __syncthreads();

    int tm = t & 15;
    int tn = t >> 4;
    float acc[4][4] = {{0.f}};
    #pragma unroll 8
    for (int k = 0; k < 64; k++) {
        float4 b = sw4[k * 16 + tn];
        float a0 = sx[tm * 4 + 0][k], a1 = sx[tm * 4 + 1][k];
        float a2 = sx[tm * 4 + 2][k], a3 = sx[tm * 4 + 3][k];
        acc[0][0] = fmaf(a0, b.x, acc[0][0]); acc[0][1] = fmaf(a0, b.y, acc[0][1]);
        acc[0][2] = fmaf(a0, b.z, acc[0][2]); acc[0][3] = fmaf(a0, b.w, acc[0][3]);
        acc[1][0] = fmaf(a1, b.x, acc[1][0]); acc[1][1] = fmaf(a1, b.y, acc[1][1]);
        acc[1][2] = fmaf(a1, b.z, acc[1][2]); acc[1][3] = fmaf(a1, b.w, acc[1][3]);
        acc[2][0] = fmaf(a2, b.x, acc[2][0]); acc[2][1] = fmaf(a2, b.y, acc[2][1]);
        acc[2][2] = fmaf(a2, b.z, acc[2][2]); acc[2][3] = fmaf(a2, b.w, acc[2][3]);
        acc[3][0] = fmaf(a3, b.x, acc[3][0]); acc[3][1] = fmaf(a3, b.y, acc[3][1]);
        acc[3][2] = fmaf(a3, b.z, acc[3][2]); acc[3][3] = fmaf(a3, b.w, acc[3][3]);
    }
    #pragma unroll
    for (int i = 0; i < 4; i++) {
        int row = base + tm * 4 + i;
        if (row < M) {
            ushort4 p;
            p.x = f32_to_bf16(acc[i][0]); p.y = f32_to_bf16(acc[i][1]);
            p.z = f32_to_bf16(acc[i][2]); p.w = f32_to_bf16(acc[i][3]);
            *(ushort4*)&Y[(size_t)row * 64 + tn * 4] = p;
        }
    }
}

// ---------- dense GEMM: Z[M,32] = H[M,64] @ W[64,32], Z stored bf16 ----------
// 128 nodes/block; tm 0..31, tn 0..7.
__global__ void __launch_bounds__(256) gemm_n32(const float4* __restrict__ X4,
                                                const float* __restrict__ W,
                                                unsigned short* __restrict__ Z, int M) {
    __shared__ float sx[128][65];
    __shared__ float sw[64 * 32];
    int t = threadIdx.x;
    int base = blockIdx.x * 128;
    for (int i = t; i < 128 * 16; i += 256) {
        int r = i >> 4, c4 = i & 15;
        int row = base + r;
        float4 v = make_float4(0.f, 0.f, 0.f, 0.f);
        if (row < M) v = X4[(size_t)row * 16 + c4];
        sx[r][c4 * 4 + 0] = v.x; sx[r][c4 * 4 + 1] = v.y;
        sx[r][c4 * 4 + 2] = v.z; sx[r][c4 * 4 + 3] = v.w;
    }
    float4* sw4 = (float4*)sw;
    const float4* W4 = (const float4*)W;
    for (int i = t; i < 64 * 8; i += 256) sw4[i] = W4[i];
    __syncthreads();

    int tm = t & 31;
    int tn = t >> 5;
    float acc[4][4] = {{0.f}};
    #pragma unroll 8
    for (int k = 0; k < 64; k++) {
        float4 b = sw4[k * 8 + tn];
        float a0 = sx[tm * 4 + 0][k], a1 = sx[tm * 4 + 1][k];
        float a2 = sx[tm * 4 + 2][k], a3 = sx[tm * 4 + 3][k];
        acc[0][0] = fmaf(a0, b.x, acc[0][0]); acc[0][1] = fmaf(a0, b.y, acc[0][1]);
        acc[0][2] = fmaf(a0, b.z, acc[0][2]); acc[0][3] = fmaf(a0, b.w, acc[0][3]);
        acc[1][0] = fmaf(a1, b.x, acc[1][0]); acc[1][1] = fmaf(a1, b.y, acc[1][1]);
        acc[1][2] = fmaf(a1, b.z, acc[1][2]); acc[1][3] = fmaf(a1, b.w, acc[1][3]);
        acc[2][0] = fmaf(a2, b.x, acc[2][0]); acc[2][1] = fmaf(a2, b.y, acc[2][1]);
        acc[2][2] = fmaf(a2, b.z, acc[2][2]); acc[2][3] = fmaf(a2, b.w, acc[2][3]);
        acc[3][0] = fmaf(a3, b.x, acc[3][0]); acc[3][1] = fmaf(a3, b.y, acc[3][1]);
        acc[3][2] = fmaf(a3, b.z, acc[3][2]); acc[3][3] = fmaf(a3, b.w, acc[3][3]);
    }
    #pragma unroll
    for (int i = 0; i < 4; i++) {
        int row = base + tm * 4 + i;
        if (row < M) {
            ushort4 p;
            p.x = f32_to_bf16(acc[i][0]); p.y = f32_to_bf16(acc[i][1]);
            p.z = f32_to_bf16(acc[i][2]); p.w = f32_to_bf16(acc[i][3]);
            *(ushort4*)&Z[(size_t)row * 32 + tn * 4] = p;
        }
    }
}

// ---------- gather1: h[n] = relu(mean_{s in N(n)} y[s] + b1), y bf16[N,64] ----
// One wave per node. 8 edge subgroups x 8 lanes; lane reads uint4 = 8 bf16.
__global__ void __launch_bounds__(256) gather_relu64(
    const uint4* __restrict__ Y4, const int* __restrict__ row_ptr,
    const int* __restrict__ col, const int* __restrict__ cnt,
    const float* __restrict__ b1, float4* __restrict__ H4, int n_nodes) {
    int n = blockIdx.x * 4 + (threadIdx.x >> 6);
    if (n >= n_nodes) return;
    int lane = threadIdx.x & 63;
    int g = lane >> 3;          // edge subgroup 0..7
    int c = lane & 7;           // 8-feature chunk 0..7
    int beg = row_ptr[n];
    int d = cnt[n];

    float acc[8] = {0.f, 0.f, 0.f, 0.f, 0.f, 0.f, 0.f, 0.f};
    for (int i = 0; i < d; i += 8) {
        int idx = i + g;
        if (idx < d) {
            int s = col[beg + idx];
            uint4 v = Y4[(size_t)s * 8 + c];
            acc[0] += bf16_lo(v.x); acc[1] += bf16_hi(v.x);
            acc[2] += bf16_lo(v.y); acc[3] += bf16_hi(v.y);
            acc[4] += bf16_lo(v.z); acc[5] += bf16_hi(v.z);
            acc[6] += bf16_lo(v.w); acc[7] += bf16_hi(v.w);
        }
    }
    #pragma unroll
    for (int m = 8; m <= 32; m <<= 1) {
        #pragma unroll
        for (int q = 0; q < 8; q++) acc[q] += __shfl_xor(acc[q], m);
    }
    float inv = 1.0f / fmaxf((float)d, 1.0f);
    const float4* b1_4 = (const float4*)b1;
    float4 ba = b1_4[c * 2], bb = b1_4[c * 2 + 1];
    if (g == 0) {
        float4 o0, o1;
        o0.x = fmaxf(fmaf(acc[0], inv, ba.x), 0.f);
        o0.y = fmaxf(fmaf(acc[1], inv, ba.y), 0.f);
        o0.z = fmaxf(fmaf(acc[2], inv, ba.z), 0.f);
        o0.w = fmaxf(fmaf(acc[3], inv, ba.w), 0.f);
        o1.x = fmaxf(fmaf(acc[4], inv, bb.x), 0.f);
        o1.y = fmaxf(fmaf(acc[5], inv, bb.y), 0.f);
        o1.z = fmaxf(fmaf(acc[6], inv, bb.z), 0.f);
        o1.w = fmaxf(fmaf(acc[7], inv, bb.w), 0.f);
        H4[(size_t)n * 16 + c * 2]     = o0;
        H4[(size_t)n * 16 + c * 2 + 1] = o1;
    }
}

// ---------- gather2: out[n] = sigmoid(mean_f(relu(mean_agg(z2)[n]+b2))*Wd+bd) --
// One wave per node. 16 edge subgroups x 4 lanes; lane reads uint4 = 8 bf16.
__global__ void __launch_bounds__(256) gather_final32(
    const uint4* __restrict__ Z4, const int* __restrict__ row_ptr,
    const int* __restrict__ col, const int* __restrict__ cnt,
    const float* __restrict__ b2, const float* __restrict__ Wd,
    const float* __restrict__ bd, float* __restrict__ out, int n_nodes) {
    int n = blockIdx.x * 4 + (threadIdx.x >> 6);
    if (n >= n_nodes) return;
    int lane = threadIdx.x & 63;
    int g = lane >> 2;          // edge subgroup 0..15
    int c = lane & 3;           // 8-feature chunk 0..3
    int beg = row_ptr[n];
    int d = cnt[n];

    float acc[8] = {0.f, 0.f, 0.f, 0.f, 0.f, 0.f, 0.f, 0.f};
    for (int i = 0; i < d; i += 16) {
        int idx = i + g;
        if (idx < d) {
            int s = col[beg + idx];
            uint4 v = Z4[(size_t)s * 4 + c];
            acc[0] += bf16_lo(v.x); acc[1] += bf16_hi(v.x);
            acc[2] += bf16_lo(v.y); acc[3] += bf16_hi(v.y);
            acc[4] += bf16_lo(v.z); acc[5] += bf16_hi(v.z);
            acc[6] += bf16_lo(v.w); acc[7] += bf16_hi(v.w);
        }
    }
    #pragma unroll
    for (int m = 4; m <= 32; m <<= 1) {
        #pragma unroll
        for (int q = 0; q < 8; q++) acc[q] += __shfl_xor(acc[q], m);
    }
    float inv = 1.0f / fmaxf((float)d, 1.0f);
    const float4* b2_4 = (const float4*)b2;
    float4 ba = b2_4[c * 2], bb = b2_4[c * 2 + 1];
    float local = 0.f;
    local += fmaxf(fmaf(acc[0], inv, ba.x), 0.f);
    local += fmaxf(fmaf(acc[1], inv, ba.y), 0.f);
    local += fmaxf(fmaf(acc[2], inv, ba.z), 0.f);
    local += fmaxf(fmaf(acc[3], inv, ba.w), 0.f);
    local += fmaxf(fmaf(acc[4], inv, bb.x), 0.f);
    local += fmaxf(fmaf(acc[5], inv, bb.y), 0.f);
    local += fmaxf(fmaf(acc[6], inv, bb.z), 0.f);
    local += fmaxf(fmaf(acc[7], inv, bb.w), 0.f);
    local += __shfl_xor(local, 1);
    local += __shfl_xor(local, 2);
    if (lane == 0) {
        float z = fmaf(local * (1.0f / 32.0f), Wd[0], bd[0]);
        out[n] = 1.0f / (1.0f + __expf(-z));
    }
}

extern "C" void kernel_launch(void* const* d_in, const int* in_sizes, int n_in,
                              void* d_out, int out_size, void* d_ws, size_t ws_size,
                              hipStream_t stream) {
    const float* x    = (const float*)d_in[0];   // [N,64]
    const int*   esrc = (const int*)d_in[1];     // [E]
    const int*   edst = (const int*)d_in[2];     // [E]
    const float* W1   = (const float*)d_in[3];   // [64,64]
    const float* b1   = (const float*)d_in[4];   // [64]
    const float* W2   = (const float*)d_in[5];   // [64,32]
    const float* b2   = (const float*)d_in[6];   // [32]
    const float* Wd   = (const float*)d_in[7];   // [1,1]
    const float* bd   = (const float*)d_in[8];   // [1]
    float* out = (float*)d_out;                  // [N,1]

    // workspace: cnt|row_ptr|cursor[N_PAD] bsum[128] col[E] | y/z2 bf16[N*64] | h f32[N*64]
    int* wi      = (int*)d_ws;
    int* cnt     = wi;
    int* row_ptr = wi + N_PAD;
    int* cursor  = wi + 2 * N_PAD;
    int* bsum    = wi + 3 * N_PAD;
    int* col     = wi + 3 * N_PAD + 128;
    unsigned short* y  = (unsigned short*)(col + N_EDGES);   // bf16 [N,64]; z2 aliases it
    unsigned short* z2 = y;                                  // bf16 [N,32]
    float* h = (float*)(y + (size_t)N_NODES * 64);           // f32 [N,64]

    hipMemsetAsync((void*)cnt, 0, N_PAD * sizeof(int), stream);

    // CSR build
    hist_kernel<<<(N_EDGES + 255) / 256, 256, 0, stream>>>(edst, cnt, N_EDGES);
    scan_reduce<<<SCAN_NB, 256, 0, stream>>>(cnt, bsum, N_NODES);
    scan_spine<<<1, 128, 0, stream>>>(bsum, SCAN_NB);
    scan_final<<<SCAN_NB, 256, 0, stream>>>(cnt, bsum, row_ptr, cursor, N_NODES);
    csr_fill<<<(N_EDGES + 255) / 256, 256, 0, stream>>>(esrc, edst, cursor, col, N_EDGES);

    // y = x @ W1 (bf16 out)
    gemm_n64<<<(N_NODES + 63) / 64, 256, 0, stream>>>((const float4*)x, W1, y, N_NODES);
    // h = relu(mean_agg(y) + b1)
    gather_relu64<<<(N_NODES + 3) / 4, 256, 0, stream>>>(
        (const uint4*)y, row_ptr, col, cnt, b1, (float4*)h, N_NODES);
    // z2 = h @ W2 (bf16 out)  — aliases y, which is dead now
    gemm_n32<<<(N_NODES + 127) / 128, 256, 0, stream>>>((const float4*)h, W2, z2, N_NODES);
    // out = sigmoid(mean(relu(mean_agg(z2) + b2)) * Wd + bd)
    gather_final32<<<(N_NODES + 3) / 4, 256, 0, stream>>>(
        (const uint4*)z2, row_ptr, col, cnt, b2, Wd, bd, out, N_NODES);
}